// Round 4
// baseline (260.240 us; speedup 1.0000x reference)
//
#include <hip/hip_runtime.h>
#include <hip/hip_bf16.h>
#include <hip/hip_cooperative_groups.h>

namespace cg = cooperative_groups;

// UVCrossAttention — MI355X (gfx950), Round 4.
//
// Algebra (verified R3): dotv[q,v] = (key@W_v^T)[q]·value[v] + key[q]·b_v;
// bilinear sampling is linear in the image -> sample SCALARS from dotv[q][.]
// as a 32x32 image; final @W_o + query fused into the sampler.
//
// R4: single cooperative dispatch (512 blocks x 256 thr, 64 KB LDS = exactly
// 2 blocks/CU co-resident; __launch_bounds__(256,2) caps VGPR<=128 so the
// cooperative occupancy requirement holds), grid.sync() between phases:
//   A: off|aw|keyp|c GEMMs (417 tile-tasks)
//   B: dotv = keyp@value^T + c  (512 tasks of 32x64)
//   C: sampler + fused output GEMM (512 tasks)
// Fallback: R3's 3-dispatch path if cooperative launch is rejected.

#define NQ   1024
#define NV   1024
#define ND   128
#define NP   4
#define IMG_W 32
#define IMG_H 32

struct KArgs {
  const float *query, *key, *value, *ref3d;
  const float *W_off, *b_off, *W_attn, *b_attn, *W_v, *b_v, *W_o, *b_o;
  float *off_ws, *aw_ws, *keyp_ws, *c_ws, *dotv_ws, *out;
};

// ---------------------------------------------------------------------------
// 64x64 tile GEMM, K=128 fully staged, A staged TRANSPOSED (sA[e][m]) so the
// inner loop is 2x ds_read_b128 + 16 FMA. 256 threads, 4x4 micro-tile.
// ---------------------------------------------------------------------------
__device__ __forceinline__ void gemm_tile64(
    const float* __restrict__ A, const float* __restrict__ B,
    int N, bool nt,
    const float* __restrict__ bias, const float* __restrict__ cvec,
    float* __restrict__ C, int m0, int n0, float* sA, float* sB) {
  const int tid = threadIdx.x;

#pragma unroll
  for (int k = 0; k < 8; ++k) {
    int c = tid + k * 256;
    int m = c & 63, e4 = c >> 6;
    const float4 v = *(const float4*)(A + (size_t)(m0 + m) * 128 + e4 * 4);
    sA[(e4 * 4 + 0) * 64 + m] = v.x;
    sA[(e4 * 4 + 1) * 64 + m] = v.y;
    sA[(e4 * 4 + 2) * 64 + m] = v.z;
    sA[(e4 * 4 + 3) * 64 + m] = v.w;
  }
  if (nt) {
#pragma unroll
    for (int k = 0; k < 8; ++k) {
      int c = tid + k * 256;
      int n = c & 63, e4 = c >> 6;
      const float4 v = *(const float4*)(B + (size_t)(n0 + n) * 128 + e4 * 4);
      sB[(e4 * 4 + 0) * 64 + n] = v.x;
      sB[(e4 * 4 + 1) * 64 + n] = v.y;
      sB[(e4 * 4 + 2) * 64 + n] = v.z;
      sB[(e4 * 4 + 3) * 64 + n] = v.w;
    }
  } else {
#pragma unroll
    for (int k = 0; k < 8; ++k) {
      int c = tid + k * 256;
      int n4 = c & 15, e = c >> 4;
      *(float4*)(sB + e * 64 + n4 * 4) =
          *(const float4*)(B + (size_t)e * N + n0 + n4 * 4);
    }
  }
  __syncthreads();

  const int tx = tid & 15, ty = tid >> 4;
  float acc[4][4] = {};
#pragma unroll 8
  for (int e = 0; e < 128; ++e) {
    const float4 a = *(const float4*)(sA + e * 64 + ty * 4);
    const float4 b = *(const float4*)(sB + e * 64 + tx * 4);
    acc[0][0] += a.x * b.x; acc[0][1] += a.x * b.y; acc[0][2] += a.x * b.z; acc[0][3] += a.x * b.w;
    acc[1][0] += a.y * b.x; acc[1][1] += a.y * b.y; acc[1][2] += a.y * b.z; acc[1][3] += a.y * b.w;
    acc[2][0] += a.z * b.x; acc[2][1] += a.z * b.y; acc[2][2] += a.z * b.z; acc[2][3] += a.z * b.w;
    acc[3][0] += a.w * b.x; acc[3][1] += a.w * b.y; acc[3][2] += a.w * b.z; acc[3][3] += a.w * b.w;
  }

  float4 bv = make_float4(0.f, 0.f, 0.f, 0.f);
  if (bias) bv = *(const float4*)(bias + n0 + tx * 4);
#pragma unroll
  for (int i = 0; i < 4; ++i) {
    const int m = m0 + ty * 4 + i;
    float cv = cvec ? cvec[m] : 0.f;
    float4 r;
    r.x = acc[i][0] + bv.x + cv;
    r.y = acc[i][1] + bv.y + cv;
    r.z = acc[i][2] + bv.z + cv;
    r.w = acc[i][3] + bv.w + cv;
    *(float4*)(C + (size_t)m * N + n0 + tx * 4) = r;
  }
}

// ---------------------------------------------------------------------------
// Phase B helper: 32x64 NT tile of dotv = keyp @ value^T + c[m]
// ---------------------------------------------------------------------------
__device__ __forceinline__ void dotv_tile32x64(
    const float* __restrict__ keyp, const float* __restrict__ value,
    const float* __restrict__ cvec, float* __restrict__ dotv,
    int m0, int n0, float* sKA, float* sVB) {
  const int tid = threadIdx.x;
#pragma unroll
  for (int k = 0; k < 4; ++k) {
    int c = tid + k * 256;
    int m = c & 31, e4 = c >> 5;
    const float4 v = *(const float4*)(keyp + (size_t)(m0 + m) * 128 + e4 * 4);
    sKA[(e4 * 4 + 0) * 32 + m] = v.x;
    sKA[(e4 * 4 + 1) * 32 + m] = v.y;
    sKA[(e4 * 4 + 2) * 32 + m] = v.z;
    sKA[(e4 * 4 + 3) * 32 + m] = v.w;
  }
#pragma unroll
  for (int k = 0; k < 8; ++k) {
    int c = tid + k * 256;
    int n = c & 63, e4 = c >> 6;
    const float4 v = *(const float4*)(value + (size_t)(n0 + n) * 128 + e4 * 4);
    sVB[(e4 * 4 + 0) * 64 + n] = v.x;
    sVB[(e4 * 4 + 1) * 64 + n] = v.y;
    sVB[(e4 * 4 + 2) * 64 + n] = v.z;
    sVB[(e4 * 4 + 3) * 64 + n] = v.w;
  }
  __syncthreads();

  const int tx = tid & 15, ty = tid >> 4;
  float acc[2][4] = {};
#pragma unroll 8
  for (int e = 0; e < 128; ++e) {
    const float2 av = *(const float2*)(sKA + e * 32 + ty * 2);
    const float4 bv = *(const float4*)(sVB + e * 64 + tx * 4);
    acc[0][0] += av.x * bv.x; acc[0][1] += av.x * bv.y;
    acc[0][2] += av.x * bv.z; acc[0][3] += av.x * bv.w;
    acc[1][0] += av.y * bv.x; acc[1][1] += av.y * bv.y;
    acc[1][2] += av.y * bv.z; acc[1][3] += av.y * bv.w;
  }
#pragma unroll
  for (int i = 0; i < 2; ++i) {
    const int m = m0 + ty * 2 + i;
    const float cv = cvec[m];
    float4 r;
    r.x = acc[i][0] + cv; r.y = acc[i][1] + cv;
    r.z = acc[i][2] + cv; r.w = acc[i][3] + cv;
    *(float4*)(dotv + (size_t)m * NV + n0 + tx * 4) = r;
  }
}

// ---------------------------------------------------------------------------
// Phase C helper: sampler + fused output GEMM for queries q0, q0+1
// ---------------------------------------------------------------------------
__device__ __forceinline__ void sample_and_out(
    const float* __restrict__ dotv, const float* __restrict__ off,
    const float* __restrict__ awr, const float* __restrict__ ref3d,
    const float* __restrict__ query, const float* __restrict__ W_o,
    const float* __restrict__ b_o, float* __restrict__ out,
    int q0, float* img /*2*1024*/, float* o1s /*2*128*/) {
  const int tid = threadIdx.x;
#pragma unroll
  for (int k = 0; k < 2; ++k) {
    int c = tid + k * 256;
    int qq = c >> 8, v4 = c & 255;
    *(float4*)(&img[qq * NV + v4 * 4]) =
        *(const float4*)(dotv + (size_t)(q0 + qq) * NV + v4 * 4);
  }
  __syncthreads();

  {
    const int qq = tid >> 7;
    const int q = q0 + qq;
    const int d = tid & 127;
    const float* im = img + qq * NV;
    const size_t qe = (size_t)q * ND + d;

    const float rx = ref3d[qe * 2 + 0];
    const float ry = ref3d[qe * 2 + 1];

    const float* awp = awr + (size_t)q * (ND * NP) + d * NP;
    const float a0 = awp[0], a1 = awp[1], a2 = awp[2], a3 = awp[3];
    const float mx = fmaxf(fmaxf(a0, a1), fmaxf(a2, a3));
    const float e0 = __expf(a0 - mx), e1 = __expf(a1 - mx),
                e2 = __expf(a2 - mx), e3 = __expf(a3 - mx);
    const float inv = 1.0f / (e0 + e1 + e2 + e3);
    const float w[4] = {e0 * inv, e1 * inv, e2 * inv, e3 * inv};

    const float* op = off + (size_t)q * (ND * NP * 2) + d * (NP * 2);

    float acc = 0.0f;
#pragma unroll
    for (int p = 0; p < NP; ++p) {
      const float x = rx * (float)IMG_W + op[p * 2 + 0] - 0.5f;
      const float y = ry * (float)IMG_H + op[p * 2 + 1] - 0.5f;
      const float xf = floorf(x), yf = floorf(y);
      const int ix0 = (int)xf, iy0 = (int)yf;
      const float wx1 = x - xf, wy1 = y - yf;
      const float wx0 = 1.0f - wx1, wy0 = 1.0f - wy1;

      float s = 0.0f;
#pragma unroll
      for (int cy = 0; cy < 2; ++cy) {
#pragma unroll
        for (int cx = 0; cx < 2; ++cx) {
          const int ix = ix0 + cx, iy = iy0 + cy;
          const bool valid = (ix >= 0) & (ix < IMG_W) & (iy >= 0) & (iy < IMG_H);
          const int cix = min(max(ix, 0), IMG_W - 1);
          const int ciy = min(max(iy, 0), IMG_H - 1);
          const float wgt = (cx ? wx1 : wx0) * (cy ? wy1 : wy0);
          s += valid ? im[ciy * IMG_W + cix] * wgt : 0.0f;
        }
      }
      acc += w[p] * s;
    }
    o1s[qq * ND + d] = acc * (1.0f / 128.0f);
  }
  __syncthreads();

  {
    const int qq = tid >> 7;
    const int q = q0 + qq;
    const int n = tid & 127;
    float acc = b_o[n] + query[(size_t)q * 128 + n];
    const float* o1 = o1s + qq * ND;
#pragma unroll 8
    for (int d = 0; d < 128; ++d)
      acc += o1[d] * W_o[(size_t)d * 128 + n];
    out[(size_t)q * 128 + n] = acc;
  }
}

// ---------------------------------------------------------------------------
// Fused cooperative kernel: 512 blocks x 256 threads, 64 KB LDS (2 blocks/CU)
// ---------------------------------------------------------------------------
__global__ __launch_bounds__(256, 2) void fused_all(KArgs a) {
  cg::grid_group grid = cg::this_grid();
  __shared__ float smem[16384];  // 64 KB
  const int b = blockIdx.x;
  const int tid = threadIdx.x;

  // ---- Phase A: input-side GEMMs (417 tasks over 512 blocks) ----
  {
    float* sA = smem;
    float* sB = smem + 8192;
    if (b < 256) {
      gemm_tile64(a.query, a.W_off, 1024, false, a.b_off, nullptr, a.off_ws,
                  (b >> 4) * 64, (b & 15) * 64, sA, sB);
    } else if (b < 384) {
      const int u = b - 256;
      gemm_tile64(a.query, a.W_attn, 512, false, a.b_attn, nullptr, a.aw_ws,
                  (u >> 3) * 64, (u & 7) * 64, sA, sB);
    } else if (b < 416) {
      const int u = b - 384;   // 32 tiles: 16 m x 2 n
      gemm_tile64(a.key, a.W_v, 128, true, nullptr, nullptr, a.keyp_ws,
                  (u >> 1) * 64, (u & 1) * 64, sA, sB);
    } else if (b == 416) {
      // c[q] = key[q] . b_v  (b_v == 0 here; kept for generality)
      for (int i = 0; i < 4; ++i) {
        const int q = tid + i * 256;
        float s = 0.f;
        for (int e = 0; e < 128; ++e) s += a.key[(size_t)q * 128 + e] * a.b_v[e];
        a.c_ws[q] = s;
      }
    }
  }
  grid.sync();

  // ---- Phase B: dotv = keyp @ value^T + c  (512 tasks of 32x64) ----
  {
    float* sKA = smem;           // 32*128 floats (16 KB)
    float* sVB = smem + 4096;    // 64*128 floats (32 KB)
    const int m0 = (b & 31) * 32;
    const int n0 = (b >> 5) * 64;
    dotv_tile32x64(a.keyp_ws, a.value, a.c_ws, a.dotv_ws, m0, n0, sKA, sVB);
  }
  grid.sync();

  // ---- Phase C: sampler + fused output GEMM (1 task/block) ----
  {
    float* img = smem;           // 2*1024
    float* o1s = smem + 2048;    // 2*128
    sample_and_out(a.dotv_ws, a.off_ws, a.aw_ws, a.ref3d, a.query,
                   a.W_o, a.b_o, a.out, b * 2, img, o1s);
  }
}

// ---------------------------------------------------------------------------
// Fallback (non-cooperative) 3-dispatch path — identical math
// ---------------------------------------------------------------------------
__global__ __launch_bounds__(256, 2) void p1_kernel(KArgs a) {
  __shared__ float smem[16384];
  float* sA = smem; float* sB = smem + 8192;
  const int t = blockIdx.x;
  if (t < 256) {
    gemm_tile64(a.query, a.W_off, 1024, false, a.b_off, nullptr, a.off_ws,
                (t >> 4) * 64, (t & 15) * 64, sA, sB);
  } else if (t < 384) {
    const int u = t - 256;
    gemm_tile64(a.query, a.W_attn, 512, false, a.b_attn, nullptr, a.aw_ws,
                (u >> 3) * 64, (u & 7) * 64, sA, sB);
  } else if (t < 416) {
    const int u = t - 384;
    gemm_tile64(a.key, a.W_v, 128, true, nullptr, nullptr, a.keyp_ws,
                (u >> 1) * 64, (u & 1) * 64, sA, sB);
  } else {
    for (int i = 0; i < 4; ++i) {
      const int q = threadIdx.x + i * 256;
      float s = 0.f;
      for (int e = 0; e < 128; ++e) s += a.key[(size_t)q * 128 + e] * a.b_v[e];
      a.c_ws[q] = s;
    }
  }
}

__global__ __launch_bounds__(256, 2) void p2_kernel(KArgs a) {
  __shared__ float smem[12288];
  const int b = blockIdx.x;
  dotv_tile32x64(a.keyp_ws, a.value, a.c_ws, a.dotv_ws,
                 (b & 31) * 32, (b >> 5) * 64, smem, smem + 4096);
}

__global__ __launch_bounds__(256) void p3_kernel(KArgs a) {
  __shared__ float smem[2304];
  sample_and_out(a.dotv_ws, a.off_ws, a.aw_ws, a.ref3d, a.query,
                 a.W_o, a.b_o, a.out, blockIdx.x * 2, smem, smem + 2048);
}

// ---------------------------------------------------------------------------
extern "C" void kernel_launch(void* const* d_in, const int* in_sizes, int n_in,
                              void* d_out, int out_size, void* d_ws, size_t ws_size,
                              hipStream_t stream) {
  float* ws = (float*)d_ws;
  KArgs a;
  a.query  = (const float*)d_in[0];
  a.key    = (const float*)d_in[1];
  a.value  = (const float*)d_in[2];
  a.ref3d  = (const float*)d_in[3];
  // d_in[4] = spatial_shapes [[32,32]] (hardcoded)
  a.W_off  = (const float*)d_in[5];
  a.b_off  = (const float*)d_in[6];
  a.W_attn = (const float*)d_in[7];
  a.b_attn = (const float*)d_in[8];
  a.W_v    = (const float*)d_in[9];
  a.b_v    = (const float*)d_in[10];
  a.W_o    = (const float*)d_in[11];
  a.b_o    = (const float*)d_in[12];
  a.off_ws  = ws;                              // 1024*1024
  a.aw_ws   = a.off_ws + (size_t)NQ * 1024;    // 1024*512
  a.keyp_ws = a.aw_ws + (size_t)NQ * 512;      // 1024*128
  a.c_ws    = a.keyp_ws + (size_t)NQ * 128;    // 1024
  a.dotv_ws = a.c_ws + 1024;                   // 1024*1024
  a.out     = (float*)d_out;

  void* kargs[] = { (void*)&a };
  hipError_t err = hipLaunchCooperativeKernel(
      (const void*)fused_all, dim3(512), dim3(256), kargs, 0, stream);
  if (err != hipSuccess) {
    // cooperative launch unsupported (or capture rejected it): 3-dispatch path
    p1_kernel<<<417, 256, 0, stream>>>(a);
    p2_kernel<<<512, 256, 0, stream>>>(a);
    p3_kernel<<<512, 256, 0, stream>>>(a);
  }
}

// Round 5
// 116.943 us; speedup vs baseline: 2.2254x; 2.2254x over previous
//
#include <hip/hip_runtime.h>
#include <hip/hip_bf16.h>

// UVCrossAttention — MI355X (gfx950), Round 5.
//
// Algebra (verified R3): dotv[q,v] = (key@W_v^T)[q]·value[v] + key[q]·b_v;
// bilinear sampling is linear in the image -> sample SCALARS from dotv[q][.]
// as a 32x32 image; final @W_o + query fused into the sampler.
//
// R5: REVERT cooperative fusion (R4: grid.sync() cost ~70us each on gfx950 —
// 151us single-kernel vs ~5-9us for the same work as 3 dispatches).
// 3 dispatches: p1 (off|aw|keyp|c, 417 blocks) -> p2 (dotv NT, 512x 32x64
// tiles = full 2-blocks/CU occupancy) -> p3 (sampler + fused out GEMM, 512).
// Measured harness floor: ~109us/iter of d_ws re-poison + restore traffic;
// kernel-side is ~5-9us.

#define NQ   1024
#define NV   1024
#define ND   128
#define NP   4
#define IMG_W 32
#define IMG_H 32

struct KArgs {
  const float *query, *key, *value, *ref3d;
  const float *W_off, *b_off, *W_attn, *b_attn, *W_v, *b_v, *W_o, *b_o;
  float *off_ws, *aw_ws, *keyp_ws, *c_ws, *dotv_ws, *out;
};

// ---------------------------------------------------------------------------
// 64x64 tile GEMM, K=128 fully staged, A staged TRANSPOSED (sA[e][m]) so the
// inner loop is 2x ds_read_b128 + 16 FMA. 256 threads, 4x4 micro-tile.
// ---------------------------------------------------------------------------
__device__ __forceinline__ void gemm_tile64(
    const float* __restrict__ A, const float* __restrict__ B,
    int N, bool nt,
    const float* __restrict__ bias, const float* __restrict__ cvec,
    float* __restrict__ C, int m0, int n0, float* sA, float* sB) {
  const int tid = threadIdx.x;

#pragma unroll
  for (int k = 0; k < 8; ++k) {
    int c = tid + k * 256;
    int m = c & 63, e4 = c >> 6;
    const float4 v = *(const float4*)(A + (size_t)(m0 + m) * 128 + e4 * 4);
    sA[(e4 * 4 + 0) * 64 + m] = v.x;
    sA[(e4 * 4 + 1) * 64 + m] = v.y;
    sA[(e4 * 4 + 2) * 64 + m] = v.z;
    sA[(e4 * 4 + 3) * 64 + m] = v.w;
  }
  if (nt) {
#pragma unroll
    for (int k = 0; k < 8; ++k) {
      int c = tid + k * 256;
      int n = c & 63, e4 = c >> 6;
      const float4 v = *(const float4*)(B + (size_t)(n0 + n) * 128 + e4 * 4);
      sB[(e4 * 4 + 0) * 64 + n] = v.x;
      sB[(e4 * 4 + 1) * 64 + n] = v.y;
      sB[(e4 * 4 + 2) * 64 + n] = v.z;
      sB[(e4 * 4 + 3) * 64 + n] = v.w;
    }
  } else {
#pragma unroll
    for (int k = 0; k < 8; ++k) {
      int c = tid + k * 256;
      int n4 = c & 15, e = c >> 4;
      *(float4*)(sB + e * 64 + n4 * 4) =
          *(const float4*)(B + (size_t)e * N + n0 + n4 * 4);
    }
  }
  __syncthreads();

  const int tx = tid & 15, ty = tid >> 4;
  float acc[4][4] = {};
#pragma unroll 8
  for (int e = 0; e < 128; ++e) {
    const float4 a = *(const float4*)(sA + e * 64 + ty * 4);
    const float4 b = *(const float4*)(sB + e * 64 + tx * 4);
    acc[0][0] += a.x * b.x; acc[0][1] += a.x * b.y; acc[0][2] += a.x * b.z; acc[0][3] += a.x * b.w;
    acc[1][0] += a.y * b.x; acc[1][1] += a.y * b.y; acc[1][2] += a.y * b.z; acc[1][3] += a.y * b.w;
    acc[2][0] += a.z * b.x; acc[2][1] += a.z * b.y; acc[2][2] += a.z * b.z; acc[2][3] += a.z * b.w;
    acc[3][0] += a.w * b.x; acc[3][1] += a.w * b.y; acc[3][2] += a.w * b.z; acc[3][3] += a.w * b.w;
  }

  float4 bv = make_float4(0.f, 0.f, 0.f, 0.f);
  if (bias) bv = *(const float4*)(bias + n0 + tx * 4);
#pragma unroll
  for (int i = 0; i < 4; ++i) {
    const int m = m0 + ty * 4 + i;
    float cv = cvec ? cvec[m] : 0.f;
    float4 r;
    r.x = acc[i][0] + bv.x + cv;
    r.y = acc[i][1] + bv.y + cv;
    r.z = acc[i][2] + bv.z + cv;
    r.w = acc[i][3] + bv.w + cv;
    *(float4*)(C + (size_t)m * N + n0 + tx * 4) = r;
  }
}

// ---------------------------------------------------------------------------
// 32x64 NT tile of dotv = keyp @ value^T + c[m]
// ---------------------------------------------------------------------------
__device__ __forceinline__ void dotv_tile32x64(
    const float* __restrict__ keyp, const float* __restrict__ value,
    const float* __restrict__ cvec, float* __restrict__ dotv,
    int m0, int n0, float* sKA, float* sVB) {
  const int tid = threadIdx.x;
#pragma unroll
  for (int k = 0; k < 4; ++k) {
    int c = tid + k * 256;
    int m = c & 31, e4 = c >> 5;
    const float4 v = *(const float4*)(keyp + (size_t)(m0 + m) * 128 + e4 * 4);
    sKA[(e4 * 4 + 0) * 32 + m] = v.x;
    sKA[(e4 * 4 + 1) * 32 + m] = v.y;
    sKA[(e4 * 4 + 2) * 32 + m] = v.z;
    sKA[(e4 * 4 + 3) * 32 + m] = v.w;
  }
#pragma unroll
  for (int k = 0; k < 8; ++k) {
    int c = tid + k * 256;
    int n = c & 63, e4 = c >> 6;
    const float4 v = *(const float4*)(value + (size_t)(n0 + n) * 128 + e4 * 4);
    sVB[(e4 * 4 + 0) * 64 + n] = v.x;
    sVB[(e4 * 4 + 1) * 64 + n] = v.y;
    sVB[(e4 * 4 + 2) * 64 + n] = v.z;
    sVB[(e4 * 4 + 3) * 64 + n] = v.w;
  }
  __syncthreads();

  const int tx = tid & 15, ty = tid >> 4;
  float acc[2][4] = {};
#pragma unroll 8
  for (int e = 0; e < 128; ++e) {
    const float2 av = *(const float2*)(sKA + e * 32 + ty * 2);
    const float4 bv = *(const float4*)(sVB + e * 64 + tx * 4);
    acc[0][0] += av.x * bv.x; acc[0][1] += av.x * bv.y;
    acc[0][2] += av.x * bv.z; acc[0][3] += av.x * bv.w;
    acc[1][0] += av.y * bv.x; acc[1][1] += av.y * bv.y;
    acc[1][2] += av.y * bv.z; acc[1][3] += av.y * bv.w;
  }
#pragma unroll
  for (int i = 0; i < 2; ++i) {
    const int m = m0 + ty * 2 + i;
    const float cv = cvec[m];
    float4 r;
    r.x = acc[i][0] + cv; r.y = acc[i][1] + cv;
    r.z = acc[i][2] + cv; r.w = acc[i][3] + cv;
    *(float4*)(dotv + (size_t)m * NV + n0 + tx * 4) = r;
  }
}

// ---------------------------------------------------------------------------
// Sampler + fused output GEMM for queries q0, q0+1
// ---------------------------------------------------------------------------
__device__ __forceinline__ void sample_and_out(
    const float* __restrict__ dotv, const float* __restrict__ off,
    const float* __restrict__ awr, const float* __restrict__ ref3d,
    const float* __restrict__ query, const float* __restrict__ W_o,
    const float* __restrict__ b_o, float* __restrict__ out,
    int q0, float* img /*2*1024*/, float* o1s /*2*128*/) {
  const int tid = threadIdx.x;
#pragma unroll
  for (int k = 0; k < 2; ++k) {
    int c = tid + k * 256;
    int qq = c >> 8, v4 = c & 255;
    *(float4*)(&img[qq * NV + v4 * 4]) =
        *(const float4*)(dotv + (size_t)(q0 + qq) * NV + v4 * 4);
  }
  __syncthreads();

  {
    const int qq = tid >> 7;
    const int q = q0 + qq;
    const int d = tid & 127;
    const float* im = img + qq * NV;
    const size_t qe = (size_t)q * ND + d;

    const float rx = ref3d[qe * 2 + 0];
    const float ry = ref3d[qe * 2 + 1];

    const float* awp = awr + (size_t)q * (ND * NP) + d * NP;
    const float a0 = awp[0], a1 = awp[1], a2 = awp[2], a3 = awp[3];
    const float mx = fmaxf(fmaxf(a0, a1), fmaxf(a2, a3));
    const float e0 = __expf(a0 - mx), e1 = __expf(a1 - mx),
                e2 = __expf(a2 - mx), e3 = __expf(a3 - mx);
    const float inv = 1.0f / (e0 + e1 + e2 + e3);
    const float w[4] = {e0 * inv, e1 * inv, e2 * inv, e3 * inv};

    const float* op = off + (size_t)q * (ND * NP * 2) + d * (NP * 2);

    float acc = 0.0f;
#pragma unroll
    for (int p = 0; p < NP; ++p) {
      const float x = rx * (float)IMG_W + op[p * 2 + 0] - 0.5f;
      const float y = ry * (float)IMG_H + op[p * 2 + 1] - 0.5f;
      const float xf = floorf(x), yf = floorf(y);
      const int ix0 = (int)xf, iy0 = (int)yf;
      const float wx1 = x - xf, wy1 = y - yf;
      const float wx0 = 1.0f - wx1, wy0 = 1.0f - wy1;

      float s = 0.0f;
#pragma unroll
      for (int cy = 0; cy < 2; ++cy) {
#pragma unroll
        for (int cx = 0; cx < 2; ++cx) {
          const int ix = ix0 + cx, iy = iy0 + cy;
          const bool valid = (ix >= 0) & (ix < IMG_W) & (iy >= 0) & (iy < IMG_H);
          const int cix = min(max(ix, 0), IMG_W - 1);
          const int ciy = min(max(iy, 0), IMG_H - 1);
          const float wgt = (cx ? wx1 : wx0) * (cy ? wy1 : wy0);
          s += valid ? im[ciy * IMG_W + cix] * wgt : 0.0f;
        }
      }
      acc += w[p] * s;
    }
    o1s[qq * ND + d] = acc * (1.0f / 128.0f);
  }
  __syncthreads();

  {
    const int qq = tid >> 7;
    const int q = q0 + qq;
    const int n = tid & 127;
    float acc = b_o[n] + query[(size_t)q * 128 + n];
    const float* o1 = o1s + qq * ND;
#pragma unroll 8
    for (int d = 0; d < 128; ++d)
      acc += o1[d] * W_o[(size_t)d * 128 + n];
    out[(size_t)q * 128 + n] = acc;
  }
}

// ---------------------------------------------------------------------------
// p1: off (256 tiles) | aw (128) | keyp (32, NT) | c (1 block)
// ---------------------------------------------------------------------------
__global__ __launch_bounds__(256, 2) void p1_kernel(KArgs a) {
  __shared__ float smem[16384];
  float* sA = smem; float* sB = smem + 8192;
  const int t = blockIdx.x;
  if (t < 256) {
    gemm_tile64(a.query, a.W_off, 1024, false, a.b_off, nullptr, a.off_ws,
                (t >> 4) * 64, (t & 15) * 64, sA, sB);
  } else if (t < 384) {
    const int u = t - 256;
    gemm_tile64(a.query, a.W_attn, 512, false, a.b_attn, nullptr, a.aw_ws,
                (u >> 3) * 64, (u & 7) * 64, sA, sB);
  } else if (t < 416) {
    const int u = t - 384;   // 32 tiles: 16 m x 2 n
    gemm_tile64(a.key, a.W_v, 128, true, nullptr, nullptr, a.keyp_ws,
                (u >> 1) * 64, (u & 1) * 64, sA, sB);
  } else {
    // c[q] = key[q] . b_v  (b_v == 0 here; kept for generality)
    for (int i = 0; i < 4; ++i) {
      const int q = threadIdx.x + i * 256;
      float s = 0.f;
      for (int e = 0; e < 128; ++e) s += a.key[(size_t)q * 128 + e] * a.b_v[e];
      a.c_ws[q] = s;
    }
  }
}

// p2: dotv = keyp @ value^T + c  (512 tiles of 32x64, 2 blocks/CU everywhere)
__global__ __launch_bounds__(256, 2) void p2_kernel(KArgs a) {
  __shared__ float smem[12288];
  const int b = blockIdx.x;
  dotv_tile32x64(a.keyp_ws, a.value, a.c_ws, a.dotv_ws,
                 (b & 31) * 32, (b >> 5) * 64, smem, smem + 4096);
}

// p3: sampler + fused output GEMM (512 blocks, 2 queries each)
__global__ __launch_bounds__(256) void p3_kernel(KArgs a) {
  __shared__ float smem[2304];
  sample_and_out(a.dotv_ws, a.off_ws, a.aw_ws, a.ref3d, a.query,
                 a.W_o, a.b_o, a.out, blockIdx.x * 2, smem, smem + 2048);
}

// ---------------------------------------------------------------------------
extern "C" void kernel_launch(void* const* d_in, const int* in_sizes, int n_in,
                              void* d_out, int out_size, void* d_ws, size_t ws_size,
                              hipStream_t stream) {
  float* ws = (float*)d_ws;
  KArgs a;
  a.query  = (const float*)d_in[0];
  a.key    = (const float*)d_in[1];
  a.value  = (const float*)d_in[2];
  a.ref3d  = (const float*)d_in[3];
  // d_in[4] = spatial_shapes [[32,32]] (hardcoded)
  a.W_off  = (const float*)d_in[5];
  a.b_off  = (const float*)d_in[6];
  a.W_attn = (const float*)d_in[7];
  a.b_attn = (const float*)d_in[8];
  a.W_v    = (const float*)d_in[9];
  a.b_v    = (const float*)d_in[10];
  a.W_o    = (const float*)d_in[11];
  a.b_o    = (const float*)d_in[12];
  a.off_ws  = ws;                              // 1024*1024
  a.aw_ws   = a.off_ws + (size_t)NQ * 1024;    // 1024*512
  a.keyp_ws = a.aw_ws + (size_t)NQ * 512;      // 1024*128
  a.c_ws    = a.keyp_ws + (size_t)NQ * 128;    // 1024
  a.dotv_ws = a.c_ws + 1024;                   // 1024*1024
  a.out     = (float*)d_out;

  p1_kernel<<<417, 256, 0, stream>>>(a);
  p2_kernel<<<512, 256, 0, stream>>>(a);
  p3_kernel<<<512, 256, 0, stream>>>(a);
}